// Round 7
// baseline (136.517 us; speedup 1.0000x reference)
//
#include <hip/hip_runtime.h>

#define NIMG     4991
#define NIMG_PAD 5055        // NIMG + 64 inert pad entries (chunk over-read safety)
#define RIRLEN   3968
#define NT       256
#define NB       256         // ti0 buckets: width 16, offset +64 -> bucket=(ti0+64)>>4
#define NWV      62          // output windows of 64 bins (RIRLEN/64)
#define SPLIT    8           // image-range eighths per window
#define GW       2048        // gather grid: 2048 blocks x 4 waves = 8192 waves
#define BPB      16          // fallback scatter blocks per batch
#define INV_PI   0.31830988618379067f
#define SR_OVER_C 46.647230320699704f   // 16000 / 343

// ---- compile-time compact image-source table: all (x,y,z), |x|+|y|+|z| <= 15 ----
struct Tab { int v[NIMG]; };
static constexpr Tab make_tab() {
    Tab t{};
    int k = 0;
    for (int x = -15; x <= 15; ++x)
        for (int y = -15; y <= 15; ++y)
            for (int z = -15; z <= 15; ++z) {
                int ax = x < 0 ? -x : x;
                int ay = y < 0 ? -y : y;
                int az = z < 0 ? -z : z;
                if (ax + ay + az <= 15)
                    t.v[k++] = (x + 15) | ((y + 15) << 8) | ((z + 15) << 16);
            }
    return t;
}
__constant__ Tab c_tab = make_tab();

static __device__ __forceinline__ int iabs(int v) { return v < 0 ? -v : v; }
static __device__ __forceinline__ float rdl(float v, int k) {
    return __int_as_float(__builtin_amdgcn_readlane(__float_as_int(v), k));
}

// ============================================================================
// K1: per-batch prep. Zeroes its output row, then emits one float4 per image,
// bucket-sorted by ti0 into ws:  {delay, Hp, Cdp, Sdp}
//   c1p = amp * (-1)^di * sin(pi*frac) / pi        (frac = ceil(delay)-delay)
//   Hp  = 0.5*c1p
//   Cdp = 0.5*c1p*cos(2*pi*(di mod 80 - frac)/80), Sdp = 0.5*c1p*sin(...)
// Gather: v(t) = (-1)^t * (Hp + cos_t*Cdp + sin_t*Sdp) / (t - delay).
// frac==0 (c1p==0; true value = amp at t=di only): direct atomic add, inert
// entry (delay=1e9 -> masked). 64 inert pad entries appended after the list.
// ============================================================================
__global__ __launch_bounds__(NT)
void rir_prep(const float* __restrict__ inp, float* __restrict__ out,
              float* __restrict__ params, int* __restrict__ offs, int B) {
    const int b   = blockIdx.x;
    const int tid = threadIdx.x;

    __shared__ float s_par[12];
    __shared__ int   s_hist[NB];
    __shared__ int   s_scan[NB];
    __shared__ int   s_off[NB + 1];

    {   // zero this batch's output row (replaces hipMemsetAsync)
        float4* orow4 = (float4*)(out + (size_t)b * RIRLEN);
        for (int t = tid; t < RIRLEN / 4; t += NT)
            orow4[t] = make_float4(0.f, 0.f, 0.f, 0.f);
    }

    s_hist[tid] = 0;
    if (tid == 0) {
        const float* ip = inp + b * 12;
        float rx = ip[0], ry = ip[1], rz = ip[2];
        float mx = ip[3] * rx, my = ip[4] * ry, mz = ip[5] * rz;
        float sx = ip[6] * rx, sy = ip[7] * ry, sz = ip[8] * rz;
        float aw = __builtin_fmaf(ip[9],  0.84f, 0.01f);
        float a4 = __builtin_fmaf(ip[10], 0.84f, 0.01f);
        float a5 = __builtin_fmaf(ip[11], 0.84f, 0.01f);
        s_par[0] = rx; s_par[1] = ry; s_par[2] = rz;
        s_par[3] = mx; s_par[4] = my; s_par[5] = mz;
        s_par[6] = sx; s_par[7] = sy; s_par[8] = sz;
        s_par[9]  = 0.5f * __builtin_amdgcn_logf(1.0f - aw);   // log2(tr)
        s_par[10] = 0.5f * __builtin_amdgcn_logf(1.0f - a4);
        s_par[11] = 0.5f * __builtin_amdgcn_logf(1.0f - a5);
        float dx = mx - sx, dy = my - sy, dz = mz - sz;
        out[(size_t)B * RIRLEN + b] = __builtin_fmaf(
            __builtin_sqrtf(dx * dx + dy * dy + dz * dz), SR_OVER_C, 40.0f);
    }
    __syncthreads();

    const float rx = s_par[0], ry = s_par[1], rz = s_par[2];
    const float mx = s_par[3], my = s_par[4], mz = s_par[5];
    const float sx = s_par[6], sy = s_par[7], sz = s_par[8];
    const float lw = s_par[9], l4 = s_par[10], l5 = s_par[11];

    // ---- pass A: histogram of ti0 buckets ----
    for (int idx = tid; idx < NIMG; idx += NT) {
        const int p = c_tab.v[idx];
        const int x = (p & 255) - 15;
        const int y = ((p >> 8) & 255) - 15;
        const int z = ((p >> 16) & 255) - 15;
        const float ix = (x & 1) ? __builtin_fmaf(rx, (float)(x + 1), -sx)
                                 : __builtin_fmaf(rx, (float)x, sx);
        const float iy = (y & 1) ? __builtin_fmaf(ry, (float)(y + 1), -sy)
                                 : __builtin_fmaf(ry, (float)y, sy);
        const float iz = (z & 1) ? __builtin_fmaf(rz, (float)(z + 1), -sz)
                                 : __builtin_fmaf(rz, (float)z, sz);
        const float dx = ix - mx, dy = iy - my, dz = iz - mz;
        const float dist  = __builtin_sqrtf(__builtin_fmaf(dx, dx, __builtin_fmaf(dy, dy, dz * dz)));
        const float delay = dist * SR_OVER_C;
        const int   ti0   = (int)__builtin_ceilf(delay) - 40;
        if (ti0 < RIRLEN) atomicAdd(&s_hist[(ti0 + 64) >> 4], 1);
    }
    __syncthreads();

    // ---- exclusive scan over NB==NT buckets (Hillis-Steele) ----
    s_scan[tid] = s_hist[tid];
    __syncthreads();
    for (int d = 1; d < NB; d <<= 1) {
        int tv = (tid >= d) ? s_scan[tid - d] : 0;
        __syncthreads();
        s_scan[tid] += tv;
        __syncthreads();
    }
    if (tid == 0) s_off[0] = 0;
    s_off[tid + 1] = s_scan[tid];
    __syncthreads();
    offs[b * (NB + 1) + tid] = s_off[tid];
    if (tid == NT - 1) offs[b * (NB + 1) + NB] = s_off[NB];
    s_hist[tid] = s_off[tid];          // reuse as per-bucket cursors
    __syncthreads();

    float4* pb = (float4*)params + (size_t)b * NIMG_PAD;

    // 64 inert pad entries after the live list (disjoint from scatter slots)
    {
        const int total = s_off[NB];
        if (tid < 64) pb[total + tid] = make_float4(1.0e9f, 0.f, 0.f, 0.f);
    }

    // ---- pass B: params, scattered into bucket-sorted order ----
    for (int idx = tid; idx < NIMG; idx += NT) {
        const int p = c_tab.v[idx];
        const int x = (p & 255) - 15;
        const int y = ((p >> 8) & 255) - 15;
        const int z = ((p >> 16) & 255) - 15;
        const float ix = (x & 1) ? __builtin_fmaf(rx, (float)(x + 1), -sx)
                                 : __builtin_fmaf(rx, (float)x, sx);
        const float iy = (y & 1) ? __builtin_fmaf(ry, (float)(y + 1), -sy)
                                 : __builtin_fmaf(ry, (float)y, sy);
        const float iz = (z & 1) ? __builtin_fmaf(rz, (float)(z + 1), -sz)
                                 : __builtin_fmaf(rz, (float)z, sz);
        const float dx = ix - mx, dy = iy - my, dz = iz - mz;
        const float dist  = __builtin_sqrtf(__builtin_fmaf(dx, dx, __builtin_fmaf(dy, dy, dz * dz)));
        const float delay = dist * SR_OVER_C;
        const float di    = __builtin_ceilf(delay);
        const int   ti0   = (int)di - 40;
        if (ti0 >= RIRLEN) continue;

        const int ew = iabs(x >> 1) + iabs((x + 1) >> 1) + iabs(y >> 1) + iabs((y + 1) >> 1);
        const float att = __builtin_amdgcn_exp2f(__builtin_fmaf((float)ew, lw,
                              __builtin_fmaf((float)iabs(z >> 1), l4,
                                   (float)iabs((z + 1) >> 1) * l5)));
        const float amp  = att * __builtin_amdgcn_rcpf(dist);
        const float frac = di - delay;                  // in [0,1), exact
        const int   dii  = (int)di;

        const int slot = atomicAdd(&s_hist[(ti0 + 64) >> 4], 1);
        float4* qptr = pb + slot;

        if (frac == 0.0f) {
            if (dii < RIRLEN) unsafeAtomicAdd(&out[(size_t)b * RIRLEN + dii], amp);
            *qptr = make_float4(1.0e9f, 0.0f, 0.0f, 0.0f);
        } else {
            float c1p = amp * __builtin_amdgcn_sinf(0.5f * frac) * INV_PI; // sin(pi*frac)/pi
            if (dii & 1) c1p = -c1p;
            const int   md   = dii - (dii / 80) * 80;        // di mod 80
            const float revd = ((float)md - frac) * 0.0125f; // revolutions
            const float Hp   = 0.5f * c1p;
            const float Cdp  = Hp * __builtin_amdgcn_cosf(revd);
            const float Sdp  = Hp * __builtin_amdgcn_sinf(revd);
            *qptr = make_float4(delay, Hp, Cdp, Sdp);
        }
    }
}

// ============================================================================
// K2: gather, snake-balanced, load-transposed. Item = (b, wv, eighth).
// Per chunk: 64 LANES LOAD 64 DIFFERENT IMAGES (coalesced 1 KB), then an
// unrolled k-loop broadcasts image k to all lanes via v_readlane (scalar pipe,
// free alongside VALU). One load feeds 64 EVALs -> L2 latency fully hidden
// even for a lone wave (fixes both stall and drain-tail). offs of item j+1
// are prefetched during item j. Ragged chunk tails exit via a uniform scalar
// branch; over-read entries are inert pads or out-of-window (masked).
// ============================================================================
__global__ __launch_bounds__(NT, 8)
void rir_gather(const float* __restrict__ params, const int* __restrict__ offs,
                float* __restrict__ out, int B) {
    const int gw   = blockIdx.x * (NT / 64) + (threadIdx.x >> 6);   // 0..8191
    const int lane = threadIdx.x & 63;
    const int bs     = B * SPLIT;
    const int nitems = bs * NWV;
    const int nj     = (nitems + 8191) >> 13;          // snake passes
    const float sl   = (lane & 1) ? -1.0f : 1.0f;      // (-1)^t, t parity = lane parity

    const float4* pp = (const float4*)params;

    // --- software-pipelined item descriptors: issue offs loads one item ahead
    int bn = 0, wvn = 0, sn = 0, lon = 0, hin = 0;
    bool vn = false;
    {
        const int r = gw;                               // j = 0 (even)
        if (r < nitems) {
            const int wvr = r / bs, rem = r - wvr * bs;
            sn = rem / B; bn = rem - sn * B; wvn = (NWV - 1) - wvr;
            const int* ob = offs + bn * (NB + 1);
            int bmin = (wvn * 64 - 16) >> 4;  if (bmin < 0) bmin = 0;
            int bmax = (wvn * 64 + 127) >> 4; if (bmax > NB - 1) bmax = NB - 1;
            lon = ob[bmin]; hin = ob[bmax + 1];
            vn = true;
        }
    }

    for (int j = 0; j < nj; ++j) {
        const bool vc = vn;
        const int  b = bn, wv = wvn, s = sn;
        const int  lo_raw = lon, hi_raw = hin;

        // prefetch next item's offs
        vn = false;
        if (j + 1 < nj) {
            const int r = ((j + 1) & 1) ? (((j + 2) << 13) - 1 - gw)
                                        : (((j + 1) << 13) + gw);
            if (r < nitems) {
                const int wvr = r / bs, rem = r - wvr * bs;
                sn = rem / B; bn = rem - sn * B; wvn = (NWV - 1) - wvr;
                const int* ob = offs + bn * (NB + 1);
                int bmin = (wvn * 64 - 16) >> 4;  if (bmin < 0) bmin = 0;
                int bmax = (wvn * 64 + 127) >> 4; if (bmax > NB - 1) bmax = NB - 1;
                lon = ob[bmin]; hin = ob[bmax + 1];
                vn = true;
            }
        }
        if (!vc) continue;

        const int lo  = __builtin_amdgcn_readfirstlane(lo_raw);
        const int hi  = __builtin_amdgcn_readfirstlane(hi_raw);
        const int len = hi - lo;
        if (len <= 0) continue;
        const int q  = (len + SPLIT - 1) >> 3;
        const int q0 = lo + s * q;
        int q1 = q0 + q; if (q1 > hi) q1 = hi;
        if (q0 >= q1) continue;

        const int   t    = wv * 64 + lane;
        const float tf   = (float)t;
        const int   m    = t - (t / 80) * 80;           // t mod 80
        const float cth0 = __builtin_amdgcn_cosf((float)m * 0.0125f);
        const float sth0 = __builtin_amdgcn_sinf((float)m * 0.0125f);

        const float4* pbb = pp + (size_t)b * NIMG_PAD;
        float4 cv = pbb[q0 + lane];                     // lane-transposed chunk
        float acc = 0.0f;

        for (int i = q0; i < q1; i += 64) {
            float4 nv = cv;
            if (i + 64 < q1) nv = pbb[i + 64 + lane];   // next chunk in flight
            const int nk = q1 - i;                      // uniform
            #pragma unroll 64
            for (int k = 0; k < 64; ++k) {
                if (k >= nk) break;                     // uniform scalar exit
                const float dly = rdl(cv.x, k);
                const float Hq  = rdl(cv.y, k);
                const float Cq  = rdl(cv.z, k);
                const float Sq  = rdl(cv.w, k);
                const float xw  = tf - dly;
                const float hp  = __builtin_fmaf(cth0, Cq,
                                      __builtin_fmaf(sth0, Sq, Hq));
                const float hm  = (__builtin_fabsf(xw) <= 40.0f) ? hp : 0.0f;
                acc = __builtin_fmaf(hm, __builtin_amdgcn_rcpf(xw), acc);
            }
            cv = nv;
        }

        const float v = sl * acc;
        if (v != 0.0f) unsafeAtomicAdd(&out[(size_t)b * RIRLEN + t], v);
    }
}

// ============================================================================
// Fallback (ws too small): scatter kernel with global-atomic epilogue.
// ============================================================================
__global__ __launch_bounds__(NT, 8)
void rir_scatter(const float* __restrict__ inp, float* __restrict__ out, int B) {
    const int b     = blockIdx.x / BPB;
    const int chunk = blockIdx.x % BPB;
    const int tid   = threadIdx.x;
    const int lane  = tid & 63;
    const int sub   = lane & 7;
    const int grp   = lane >> 3;
    const int wave  = tid >> 6;

    __shared__ float s_rir[RIRLEN];
    __shared__ float s_par[12];
    __shared__ int   s_list[320];
    __shared__ int   s_cnt;

    for (int t = tid; t < RIRLEN; t += NT) s_rir[t] = 0.0f;
    if (tid == 0) {
        s_cnt = 0;
        const float* ip = inp + b * 12;
        float rx = ip[0], ry = ip[1], rz = ip[2];
        float mx = ip[3] * rx, my = ip[4] * ry, mz = ip[5] * rz;
        float sx = ip[6] * rx, sy = ip[7] * ry, sz = ip[8] * rz;
        float aw = __builtin_fmaf(ip[9],  0.84f, 0.01f);
        float a4 = __builtin_fmaf(ip[10], 0.84f, 0.01f);
        float a5 = __builtin_fmaf(ip[11], 0.84f, 0.01f);
        s_par[0] = rx; s_par[1] = ry; s_par[2] = rz;
        s_par[3] = mx; s_par[4] = my; s_par[5] = mz;
        s_par[6] = sx; s_par[7] = sy; s_par[8] = sz;
        s_par[9]  = 0.5f * __builtin_amdgcn_logf(1.0f - aw);
        s_par[10] = 0.5f * __builtin_amdgcn_logf(1.0f - a4);
        s_par[11] = 0.5f * __builtin_amdgcn_logf(1.0f - a5);
        if (chunk == 0) {
            float dx = mx - sx, dy = my - sy, dz = mz - sz;
            out[(size_t)B * RIRLEN + b] = __builtin_fmaf(
                __builtin_sqrtf(dx * dx + dy * dy + dz * dz), SR_OVER_C, 40.0f);
        }
    }
    __syncthreads();

    const float rx = s_par[0], ry = s_par[1], rz = s_par[2];
    const float mx = s_par[3], my = s_par[4], mz = s_par[5];
    const float sx = s_par[6], sy = s_par[7], sz = s_par[8];
    const float lw = s_par[9], l4 = s_par[10], l5 = s_par[11];

    for (int k = tid; ; k += NT) {
        const int idx = chunk + k * BPB;
        if (idx >= NIMG) break;
        const int p = c_tab.v[idx];
        const int x = (p & 255) - 15;
        const int y = ((p >> 8) & 255) - 15;
        const int z = ((p >> 16) & 255) - 15;
        const float ix = (x & 1) ? __builtin_fmaf(rx, (float)(x + 1), -sx)
                                 : __builtin_fmaf(rx, (float)x, sx);
        const float iy = (y & 1) ? __builtin_fmaf(ry, (float)(y + 1), -sy)
                                 : __builtin_fmaf(ry, (float)y, sy);
        const float iz = (z & 1) ? __builtin_fmaf(rz, (float)(z + 1), -sz)
                                 : __builtin_fmaf(rz, (float)z, sz);
        const float dx = ix - mx, dy = iy - my, dz = iz - mz;
        const float d2 = __builtin_fmaf(dx, dx, __builtin_fmaf(dy, dy, dz * dz));
        if (d2 <= 7380.0f) {
            const int slot = atomicAdd(&s_cnt, 1);
            s_list[slot] = p;
        }
    }
    __syncthreads();
    const int cnt = s_cnt;

    float cj[10], sj[10];
    #pragma unroll
    for (int k = 0; k < 10; ++k) {
        const float rev = (float)(sub + 8 * k - 40) * (1.0f / 80.0f);
        cj[k] = __builtin_amdgcn_cosf(rev);
        sj[k] = __builtin_amdgcn_sinf(rev);
    }
    const float slane = (sub & 1) ? -INV_PI : INV_PI;

    for (int base = wave * 8; base < cnt; base += 32) {
        const int e = base + grp;
        const int p = s_list[e < cnt ? e : cnt - 1];
        const int x = (p & 255) - 15;
        const int y = ((p >> 8) & 255) - 15;
        const int z = ((p >> 16) & 255) - 15;
        const float ix = (x & 1) ? __builtin_fmaf(rx, (float)(x + 1), -sx)
                                 : __builtin_fmaf(rx, (float)x, sx);
        const float iy = (y & 1) ? __builtin_fmaf(ry, (float)(y + 1), -sy)
                                 : __builtin_fmaf(ry, (float)y, sy);
        const float iz = (z & 1) ? __builtin_fmaf(rz, (float)(z + 1), -sz)
                                 : __builtin_fmaf(rz, (float)z, sz);
        const float dx = ix - mx, dy = iy - my, dz = iz - mz;
        const float dist  = __builtin_sqrtf(__builtin_fmaf(dx, dx, __builtin_fmaf(dy, dy, dz * dz)));
        const float delay = dist * SR_OVER_C;
        const float di    = __builtin_ceilf(delay);
        const int   ti0   = (int)di - 40;
        const int ew = iabs(x >> 1) + iabs((x + 1) >> 1) + iabs(y >> 1) + iabs((y + 1) >> 1);
        const float att = __builtin_amdgcn_exp2f(__builtin_fmaf((float)ew, lw,
                              __builtin_fmaf((float)iabs(z >> 1), l4,
                                   (float)iabs((z + 1) >> 1) * l5)));
        float amp = att * __builtin_amdgcn_rcpf(dist);
        if (e >= cnt) amp = 0.0f;
        const float frac = di - delay;
        const float c1  = amp * __builtin_amdgcn_sinf(0.5f * frac) * slane;
        const float ca  = 0.5f * __builtin_amdgcn_cosf(frac * (1.0f / 80.0f));
        const float nsa = -0.5f * __builtin_amdgcn_sinf(frac * (1.0f / 80.0f));
        const float x0 = frac + (float)(sub - 40);
        const int   t0 = ti0 + sub;
        #pragma unroll
        for (int k = 0; k < 10; ++k) {
            const float xv = x0 + (float)(8 * k);
            const float h = __builtin_fmaf(ca, cj[k], __builtin_fmaf(nsa, sj[k], 0.5f));
            float v = c1 * h * __builtin_amdgcn_rcpf(xv);
            v = (xv == 0.0f) ? amp : v;
            const int t = t0 + 8 * k;
            if ((unsigned)t < (unsigned)RIRLEN) atomicAdd(&s_rir[t], v);
        }
    }
    __syncthreads();

    float* orow = out + (size_t)b * RIRLEN;
    for (int t = tid; t < RIRLEN; t += NT) {
        const float v = s_rir[t];
        if (v != 0.0f) atomicAdd(&orow[t], v);
    }
}

extern "C" void kernel_launch(void* const* d_in, const int* in_sizes, int n_in,
                              void* d_out, int out_size, void* d_ws, size_t ws_size,
                              hipStream_t stream) {
    const float* inp = (const float*)d_in[0];
    float* out = (float*)d_out;
    const int B = in_sizes[0] / 12;

    const size_t params_bytes = (size_t)B * NIMG_PAD * 4 * sizeof(float);
    const size_t offs_bytes   = (size_t)B * (NB + 1) * sizeof(int);
    const int use_ws = (d_ws != nullptr && ws_size >= params_bytes + offs_bytes) ? 1 : 0;

    if (use_ws) {
        float* params = (float*)d_ws;
        int*   offs   = (int*)((char*)d_ws + params_bytes);
        rir_prep  <<<dim3(B),  dim3(NT), 0, stream>>>(inp, out, params, offs, B);
        rir_gather<<<dim3(GW), dim3(NT), 0, stream>>>(params, offs, out, B);
    } else {
        (void)hipMemsetAsync(d_out, 0, (size_t)out_size * sizeof(float), stream);
        rir_scatter<<<dim3(B * BPB), dim3(NT), 0, stream>>>(inp, out, B);
    }
}